// Round 15
// baseline (124.174 us; speedup 1.0000x reference)
//
#include <hip/hip_runtime.h>

#define HH 128
#define NT 512
#define PT 256

typedef float  f32x4  __attribute__((ext_vector_type(4)));
typedef _Float16 f16x8 __attribute__((ext_vector_type(8)));
typedef _Float16 f16x2 __attribute__((ext_vector_type(2)));

// pack two f32 -> one u32 of 2 fp16 (RTZ) in a single v_cvt_pkrtz_f16_f32
static __device__ __forceinline__ unsigned int pkrtz(float a, float b){
  auto r = __builtin_amdgcn_cvt_pkrtz(a, b);   // __fp16 ext_vector(2)
  return __builtin_bit_cast(unsigned int, r);
}
// split two fp32 into fp16 hi-pair and fp16 lo-pair (22-bit total precision)
static __device__ __forceinline__ void fsplit2(float x0, float x1,
                                               unsigned int& hp, unsigned int& lp){
  hp = pkrtz(x0, x1);
  f16x2 h = __builtin_bit_cast(f16x2, hp);
  lp = pkrtz(x0 - (float)h[0], x1 - (float)h[1]);
}
static __device__ __forceinline__ float f16_to_f(unsigned short s){
  return (float)__builtin_bit_cast(_Float16, s);
}

__device__ __forceinline__ float sigf(float x){
  float t = __builtin_amdgcn_exp2f(-1.44269504089f * x);
  return __builtin_amdgcn_rcpf(1.f + t);
}
__device__ __forceinline__ float tanhf_(float x){
  float t = __builtin_amdgcn_exp2f(2.88539008178f * x);
  return 1.f - 2.f*__builtin_amdgcn_rcpf(t + 1.f);
}

// Pack W into MFMA-B-fragment order, single fp16 RNE plane each.
//  eff (internal): we = W[g][k] + 0.5*W[g][128+k];  leaf: wl = W[g][128+k]
// Pack index: (((wp*8 + q*2 + ft)*4 + kc)*64 + lane)*8 + j
__global__ __launch_bounds__(PT) void prep_pack(
    const float* __restrict__ W,
    unsigned short* __restrict__ pE, unsigned short* __restrict__ pL)
{
  int idx = blockIdx.x*PT + threadIdx.x;     // 0..8191
  int l  = idx & 63;
  int kc = (idx >> 6) & 3;
  int gl = (idx >> 8) & 7;
  int wp = (idx >> 11);                      // 0..3
  int q  = gl >> 1, ft = gl & 1;
  int g  = q*128 + wp*32 + ft*16 + (l & 15);
  int kbase = kc*32 + (l >> 4)*8;

  unsigned short ev[8], lv[8];
#pragma unroll
  for (int j = 0; j < 8; ++j){
    int k = kbase + j;
    float w0 = W[g*256 + k];
    float w1 = W[g*256 + 128 + k];
    float we = w0 + 0.5f*w1;
    ev[j] = __builtin_bit_cast(unsigned short, (_Float16)we);
    lv[j] = __builtin_bit_cast(unsigned short, (_Float16)w1);
  }
  long base = (long)idx*8;
  *(f16x8*)&pE[base] = *(f16x8*)ev;
  *(f16x8*)&pL[base] = *(f16x8*)lv;
}

// ---------------- leaf kernel: L0 only, resident fp16 leaf-B (48 VGPR) ------
__global__ __launch_bounds__(NT, 2) void leafK(
    const float* __restrict__ x_leaf,
    const unsigned short* __restrict__ pL,
    const float* __restrict__ bias,
    unsigned short* __restrict__ HpO, unsigned short* __restrict__ LpO,
    float* __restrict__ csO, int ntiles)
{
  __shared__ unsigned short AsH[2][32*HH];
  __shared__ unsigned short AsL[2][32*HH];

  const int t = threadIdx.x, w = t>>6, l = t&63;
  const int a = l>>4, fcol = l&15, feat = w*16 + fcol;

  // resident leaf-B (gates i,g,o): 12 frags = 48 VGPRs
  f16x8 rb[3][4];
#pragma unroll
  for (int qq = 0; qq < 3; ++qq)
#pragma unroll
    for (int kc = 0; kc < 4; ++kc){
      long off = ((long)((((w>>1)*8) + (qq+1)*2 + (w&1))*4 + kc)*64 + l)*8;
      rb[qq][kc] = *(const f16x8*)&pL[off];
    }
  const float Bi = bias[HH + feat], Bg = bias[2*HH + feat], Bo = bias[3*HH + feat];

  const int srow = t>>4, sci = t&15;
  float sv[8];
  auto sload = [&](int tile){
    long base = ((long)tile*32 + srow)*HH + sci*8;
    *(float4*)&sv[0] = *(const float4*)&x_leaf[base];
    *(float4*)&sv[4] = *(const float4*)&x_leaf[base+4];
  };
  auto swrite = [&](int buf){
    unsigned int hp[4], lp[4];
#pragma unroll
    for (int p = 0; p < 4; ++p) fsplit2(sv[2*p], sv[2*p+1], hp[p], lp[p]);
    uint4 hq = {hp[0],hp[1],hp[2],hp[3]};
    uint4 lq = {lp[0],lp[1],lp[2],lp[3]};
    int off = srow*256 + ((sci*16) ^ ((srow&7)<<4));
    *(uint4*)((char*)&AsH[buf][0] + off) = hq;
    *(uint4*)((char*)&AsL[buf][0] + off) = lq;
  };

  int tile = blockIdx.x;
  if (tile < ntiles){ sload(tile); swrite(0); }
  __syncthreads();
  int buf = 0;

  for (; tile < ntiles; tile += gridDim.x){
    // keep B loop-carried
#pragma unroll
    for (int qq = 0; qq < 3; ++qq)
#pragma unroll
      for (int kc = 0; kc < 4; ++kc)
        asm volatile("" : "+v"(rb[qq][kc]));

    int nxt = tile + gridDim.x;
    bool have = nxt < ntiles;
    if (have) sload(nxt);

    f32x4 acc[2][3];
#pragma unroll
    for (int mt = 0; mt < 2; ++mt)
#pragma unroll
      for (int qq = 0; qq < 3; ++qq) acc[mt][qq] = (f32x4)(0.f);

#pragma unroll
    for (int kc = 0; kc < 4; ++kc){
      f16x8 aH[2], aL[2];
#pragma unroll
      for (int mt = 0; mt < 2; ++mt){
        int row = mt*16 + fcol;
        int off = row*256 + ((kc*64 + a*16) ^ ((row&7)<<4));
        aH[mt] = *(const f16x8*)((const char*)&AsH[buf][0] + off);
        aL[mt] = *(const f16x8*)((const char*)&AsL[buf][0] + off);
      }
#pragma unroll
      for (int qq = 0; qq < 3; ++qq)
#pragma unroll
        for (int mt = 0; mt < 2; ++mt)
          acc[mt][qq] = __builtin_amdgcn_mfma_f32_16x16x32_f16(aH[mt], rb[qq][kc], acc[mt][qq], 0, 0, 0);
#pragma unroll
      for (int qq = 0; qq < 3; ++qq)
#pragma unroll
        for (int mt = 0; mt < 2; ++mt)
          acc[mt][qq] = __builtin_amdgcn_mfma_f32_16x16x32_f16(aL[mt], rb[qq][kc], acc[mt][qq], 0, 0, 0);
    }

    // epilogue (cc = 0): pair-sum fp16 hi/lo planes + f32 cs plane
#pragma unroll
    for (int mt = 0; mt < 2; ++mt){
      float hv[4], cv[4];
#pragma unroll
      for (int rr = 0; rr < 4; ++rr){
        float iv = acc[mt][0][rr] + Bi;
        float gv = acc[mt][1][rr] + Bg;
        float ov = acc[mt][2][rr] + Bo;
        float c = sigf(iv)*tanhf_(gv);
        float h = sigf(ov)*tanhf_(c);
        hv[rr] = h; cv[rr] = c;
      }
#pragma unroll
      for (int p = 0; p < 2; ++p){
        long prow = (long)tile*16 + mt*8 + a*2 + p;
        float hs = hv[2*p] + hv[2*p+1];
        _Float16 hi = (_Float16)hs;
        HpO[prow*HH + feat] = __builtin_bit_cast(unsigned short, hi);
        LpO[prow*HH + feat] = __builtin_bit_cast(unsigned short, (_Float16)(hs - (float)hi));
        csO[prow*HH + feat] = cv[2*p] + cv[2*p+1];
      }
    }

    if (have) swrite(buf^1);
    __syncthreads();
    buf ^= 1;
  }
}

// ---------------- fused 2-level internal kernel, resident fp16 eff-B --------
__global__ __launch_bounds__(NT, 2) void fuse2(
    const unsigned short* __restrict__ hPH, const unsigned short* __restrict__ hPL,
    const float* __restrict__ cP,
    const unsigned short* __restrict__ pE,
    const float* __restrict__ bias,
    unsigned short* __restrict__ HpO, unsigned short* __restrict__ LpO,
    float* __restrict__ csO, int ntiles)
{
  __shared__ unsigned short AsH[2][32*HH];
  __shared__ unsigned short AsL[2][32*HH];
  __shared__ float HsF[16*HH];
  __shared__ float CsF[16*HH];

  const int t = threadIdx.x, w = t>>6, l = t&63;
  const int a = l>>4, fcol = l&15, feat = w*16 + fcol;

  f16x8 rb[4][4];   // 16 frags = 64 VGPR
#pragma unroll
  for (int q = 0; q < 4; ++q)
#pragma unroll
    for (int kc = 0; kc < 4; ++kc){
      long off = ((long)((((w>>1)*8) + q*2 + (w&1))*4 + kc)*64 + l)*8;
      rb[q][kc] = *(const f16x8*)&pE[off];
    }
  float B4[4];
#pragma unroll
  for (int q = 0; q < 4; ++q) B4[q] = bias[q*HH + feat];

  const int srow = t>>4, sci = t&15;
  f16x8 svH, svL;
  auto sload = [&](int tile){
    long base = ((long)tile*32 + srow)*HH + sci*8;
    svH = *(const f16x8*)&hPH[base];
    svL = *(const f16x8*)&hPL[base];
  };
  auto swrite = [&](int buf){
    int off = srow*256 + ((sci*16) ^ ((srow&7)<<4));
    *(f16x8*)((char*)&AsH[buf][0] + off) = svH;
    *(f16x8*)((char*)&AsL[buf][0] + off) = svL;
  };

  int tile = blockIdx.x;
  if (tile < ntiles){ sload(tile); swrite(0); }
  __syncthreads();
  int buf = 0;

  for (; tile < ntiles; tile += gridDim.x){
#pragma unroll
    for (int q = 0; q < 4; ++q)
#pragma unroll
      for (int kc = 0; kc < 4; ++kc)
        asm volatile("" : "+v"(rb[q][kc]));

    int nxt = tile + gridDim.x;
    bool have = nxt < ntiles;

    float cc0[2][4];
#pragma unroll
    for (int mt = 0; mt < 2; ++mt)
#pragma unroll
      for (int rr = 0; rr < 4; ++rr)
        cc0[mt][rr] = cP[((long)tile*32 + mt*16 + a*4 + rr)*HH + feat];

    if (have) sload(nxt);

    // ---- MFMA-0: level A over 32 rows ----
    f32x4 acc0[2][4];
#pragma unroll
    for (int mt = 0; mt < 2; ++mt)
#pragma unroll
      for (int q = 0; q < 4; ++q) acc0[mt][q] = (f32x4)(0.f);

#pragma unroll
    for (int kc = 0; kc < 4; ++kc){
      f16x8 aH[2], aL[2];
#pragma unroll
      for (int mt = 0; mt < 2; ++mt){
        int row = mt*16 + fcol;
        int off = row*256 + ((kc*64 + a*16) ^ ((row&7)<<4));
        aH[mt] = *(const f16x8*)((const char*)&AsH[buf][0] + off);
        aL[mt] = *(const f16x8*)((const char*)&AsL[buf][0] + off);
      }
#pragma unroll
      for (int q = 0; q < 4; ++q)
#pragma unroll
        for (int mt = 0; mt < 2; ++mt)
          acc0[mt][q] = __builtin_amdgcn_mfma_f32_16x16x32_f16(aH[mt], rb[q][kc], acc0[mt][q], 0, 0, 0);
#pragma unroll
      for (int q = 0; q < 4; ++q)
#pragma unroll
        for (int mt = 0; mt < 2; ++mt)
          acc0[mt][q] = __builtin_amdgcn_mfma_f32_16x16x32_f16(aL[mt], rb[q][kc], acc0[mt][q], 0, 0, 0);
    }

    // ---- epilogue-0 -> LDS pair-sums (swizzled fp32) ----
#pragma unroll
    for (int mt = 0; mt < 2; ++mt){
      float hv[4], cv[4];
#pragma unroll
      for (int rr = 0; rr < 4; ++rr){
        float fv = acc0[mt][0][rr] + B4[0];
        float iv = acc0[mt][1][rr] + B4[1];
        float gv = acc0[mt][2][rr] + B4[2];
        float ov = acc0[mt][3][rr] + B4[3];
        float c = sigf(fv)*cc0[mt][rr] + sigf(iv)*tanhf_(gv);
        float h = sigf(ov)*tanhf_(c);
        hv[rr] = h; cv[rr] = c;
      }
#pragma unroll
      for (int p = 0; p < 2; ++p){
        int row1 = mt*8 + a*2 + p;
        int o1 = row1*512 + ((feat*4) ^ ((row1&7)<<4));
        *(float*)((char*)HsF + o1) = hv[2*p] + hv[2*p+1];
        *(float*)((char*)CsF + o1) = cv[2*p] + cv[2*p+1];
      }
    }
    if (have) swrite(buf^1);
    __syncthreads();

    // ---- MFMA-1: level B over 16 rows ----
    f32x4 acc1[4];
#pragma unroll
    for (int q = 0; q < 4; ++q) acc1[q] = (f32x4)(0.f);

#pragma unroll
    for (int kc = 0; kc < 4; ++kc){
      f16x8 a1H, a1L;
      {
        int cb = kc*128 + a*32;
        const char* base = (const char*)HsF + fcol*512;
        float av[8];
        *(float4*)&av[0] = *(const float4*)(base + ( cb       ^ ((fcol&7)<<4)));
        *(float4*)&av[4] = *(const float4*)(base + ((cb + 16) ^ ((fcol&7)<<4)));
        unsigned int hp[4], lp[4];
#pragma unroll
        for (int p = 0; p < 4; ++p) fsplit2(av[2*p], av[2*p+1], hp[p], lp[p]);
        uint4 hq = {hp[0],hp[1],hp[2],hp[3]};
        uint4 lq = {lp[0],lp[1],lp[2],lp[3]};
        a1H = *(f16x8*)&hq;
        a1L = *(f16x8*)&lq;
      }
#pragma unroll
      for (int q = 0; q < 4; ++q)
        acc1[q] = __builtin_amdgcn_mfma_f32_16x16x32_f16(a1H, rb[q][kc], acc1[q], 0, 0, 0);
#pragma unroll
      for (int q = 0; q < 4; ++q)
        acc1[q] = __builtin_amdgcn_mfma_f32_16x16x32_f16(a1L, rb[q][kc], acc1[q], 0, 0, 0);
    }

    // ---- epilogue-1 -> global planes ----
    {
      float hv[4], cv[4];
#pragma unroll
      for (int rr = 0; rr < 4; ++rr){
        int n = a*4 + rr;
        float ccv = *(const float*)((const char*)CsF + n*512 + ((feat*4) ^ ((n&7)<<4)));
        float fv = acc1[0][rr] + B4[0];
        float iv = acc1[1][rr] + B4[1];
        float gv = acc1[2][rr] + B4[2];
        float ov = acc1[3][rr] + B4[3];
        float c = sigf(fv)*ccv + sigf(iv)*tanhf_(gv);
        float h = sigf(ov)*tanhf_(c);
        hv[rr] = h; cv[rr] = c;
      }
#pragma unroll
      for (int p = 0; p < 2; ++p){
        long prow = (long)tile*8 + a*2 + p;
        float hs = hv[2*p] + hv[2*p+1];
        _Float16 hi = (_Float16)hs;
        HpO[prow*HH + feat] = __builtin_bit_cast(unsigned short, hi);
        LpO[prow*HH + feat] = __builtin_bit_cast(unsigned short, (_Float16)(hs - (float)hi));
        csO[prow*HH + feat] = cv[2*p] + cv[2*p+1];
      }
    }
    __syncthreads();
    buf ^= 1;
  }
}

// ---------------- multi-level tail block (generic) --------------------------
template<int ROWS0, int NLEV, int INPLANES, int FINAL>
__global__ __launch_bounds__(NT, 2) void treeblk2(
    const unsigned short* __restrict__ Hp, const unsigned short* __restrict__ Lp,
    const float* __restrict__ cs,
    const float* __restrict__ hraw, const float* __restrict__ craw,
    const unsigned short* __restrict__ pE,
    const float* __restrict__ bias,
    float* __restrict__ h_out, float* __restrict__ c_out,
    float* __restrict__ root_out)
{
  constexpr int MT = (ROWS0 >= 16) ? (ROWS0/16) : 1;
  __shared__ float Asum[ROWS0][132];
  __shared__ float Csum[ROWS0][132];

  const int t = threadIdx.x;
  const long blk = blockIdx.x;
  const int w = t >> 6, l = t & 63;
  const int a = l >> 4, fcol = l & 15, feat = w*16 + fcol;

  {
    constexpr int EPT = ROWS0*HH/NT;
    constexpr int TPR = HH/EPT;
    int row = t/TPR, c0 = (t%TPR)*EPT;
    if (INPLANES){
      long base = (blk*ROWS0 + row)*(long)HH + c0;
#pragma unroll
      for (int j = 0; j < EPT; ++j){
        Asum[row][c0+j] = f16_to_f(Hp[base+j]) + f16_to_f(Lp[base+j]);
        Csum[row][c0+j] = cs[base+j];
      }
    } else {
      long g = (blk*2*ROWS0 + 2*row)*(long)HH + c0;
#pragma unroll
      for (int j = 0; j < EPT; ++j){
        Asum[row][c0+j] = hraw[g+j] + hraw[g+HH+j];
        Csum[row][c0+j] = craw[g+j] + craw[g+HH+j];
      }
    }
  }

  f16x8 rb[4][4];
#pragma unroll
  for (int q = 0; q < 4; ++q)
#pragma unroll
    for (int kc = 0; kc < 4; ++kc){
      long off = ((long)((((w>>1)*8) + q*2 + (w&1))*4 + kc)*64 + l)*8;
      rb[q][kc] = *(const f16x8*)&pE[off];
    }
  float B4[4];
#pragma unroll
  for (int q = 0; q < 4; ++q) B4[q] = bias[q*HH + feat];

  __syncthreads();

#pragma unroll
  for (int lv = 0; lv < NLEV; ++lv){
    const int rows  = ROWS0 >> lv;
    const int tiles = (rows >= 16) ? (rows/16) : 1;
    float hv[MT][4], cv[MT][4];

#pragma unroll
    for (int mt = 0; mt < MT; ++mt){
      if (mt >= tiles) continue;
      f16x8 aH[4], aL[4];
#pragma unroll
      for (int kc = 0; kc < 4; ++kc){
        const float* ap = &Asum[mt*16 + fcol][kc*32 + a*8];
        float av[8];
        *(float4*)&av[0] = *(const float4*)&ap[0];
        *(float4*)&av[4] = *(const float4*)&ap[4];
        unsigned int hp[4], lp[4];
#pragma unroll
        for (int p = 0; p < 4; ++p) fsplit2(av[2*p], av[2*p+1], hp[p], lp[p]);
        uint4 hq = {hp[0],hp[1],hp[2],hp[3]};
        uint4 lq = {lp[0],lp[1],lp[2],lp[3]};
        aH[kc] = *(f16x8*)&hq;
        aL[kc] = *(f16x8*)&lq;
      }
      f32x4 acc[4];
#pragma unroll
      for (int q = 0; q < 4; ++q) acc[q] = (f32x4)(0.f);
#pragma unroll
      for (int kc = 0; kc < 4; ++kc){
#pragma unroll
        for (int q = 0; q < 4; ++q)
          acc[q] = __builtin_amdgcn_mfma_f32_16x16x32_f16(aH[kc], rb[q][kc], acc[q], 0, 0, 0);
#pragma unroll
        for (int q = 0; q < 4; ++q)
          acc[q] = __builtin_amdgcn_mfma_f32_16x16x32_f16(aL[kc], rb[q][kc], acc[q], 0, 0, 0);
      }
#pragma unroll
      for (int rr = 0; rr < 4; ++rr){
        int n = mt*16 + a*4 + rr;
        float ccv = Csum[n][feat];
        float fv = acc[0][rr] + B4[0];
        float iv = acc[1][rr] + B4[1];
        float gv = acc[2][rr] + B4[2];
        float ov = acc[3][rr] + B4[3];
        float c = sigf(fv)*ccv + sigf(iv)*tanhf_(gv);
        float h = sigf(ov)*tanhf_(c);
        hv[mt][rr] = h; cv[mt][rr] = c;
      }
    }
    __syncthreads();

    if (lv < NLEV-1){
#pragma unroll
      for (int mt = 0; mt < MT; ++mt){
        if (mt >= tiles) continue;
#pragma unroll
        for (int p = 0; p < 2; ++p){
          int n0 = mt*16 + a*4 + 2*p;
          if (n0 < rows){
            int prow = n0 >> 1;
            Asum[prow][feat] = hv[mt][2*p] + hv[mt][2*p+1];
            Csum[prow][feat] = cv[mt][2*p] + cv[mt][2*p+1];
          }
        }
      }
      __syncthreads();
    } else if (FINAL){
      if (a == 0) root_out[feat] = hv[0][0];
    } else {
      if (a == 0){
        h_out[blk*HH + feat] = hv[0][0];
        c_out[blk*HH + feat] = cv[0][0];
      }
    }
  }
}

extern "C" void kernel_launch(void* const* d_in, const int* in_sizes, int n_in,
                              void* d_out, int out_size, void* d_ws, size_t ws_size,
                              hipStream_t stream){
  const float* leaf = (const float*)d_in[0];   // 131072 x 128 f32
  const float* W    = (const float*)d_in[1];   // 512 x 256 f32
  const float* bias = (const float*)d_in[2];   // 512 f32
  float* out = (float*)d_out;                  // 128 f32

  unsigned short* pE  = (unsigned short*)d_ws;      // 65536 u16 each
  unsigned short* pL  = pE + 65536;
  unsigned short* HpA = pL + 65536;                 // 2^16 x 128 u16
  unsigned short* LpA = HpA + (1l<<16)*HH;
  unsigned short* HpB = LpA + (1l<<16)*HH;          // 2^14 x 128 u16
  unsigned short* LpB = HpB + (1l<<14)*HH;
  float* csA = (float*)(LpB + (1l<<14)*HH);         // 2^16 x 128 f32
  float* csB = csA + (1l<<16)*HH;                   // 2^14 x 128 f32
  float* h32 = csB + (1l<<14)*HH;                   // 32 x 128 f32
  float* c32 = h32 + 32*HH;

  prep_pack<<<32, PT, 0, stream>>>(W, pE, pL);

  // L0: 2^17 leaves -> 2^16 pair-rows (4 blocks/CU co-resident: 32KB LDS, 56 VGPR)
  leafK<<<1024, NT, 0, stream>>>(leaf, pL, bias, HpA, LpA, csA, 4096);
  // L1+L2: 2^16 rows -> 2^14 (3 blocks/CU: 48KB LDS)
  fuse2<<<1024, NT, 0, stream>>>(HpA, LpA, csA, pE, bias, HpB, LpB, csB, 2048);
  // L3+L4: 2^14 -> 2^12
  fuse2<<<512, NT, 0, stream>>>(HpB, LpB, csB, pE, bias, HpA, LpA, csA, 512);
  // L5+L6: 2^12 -> 2^10
  fuse2<<<128, NT, 0, stream>>>(HpA, LpA, csA, pE, bias, HpB, LpB, csB, 128);
  // L7..L12: 2^10 pair-rows -> 32 raw nodes
  treeblk2<32,6,1,0><<<32, NT, 0, stream>>>(HpB, LpB, csB, nullptr, nullptr,
                                            pE, bias, h32, c32, nullptr);
  // L13..L17: 32 raw children -> root
  treeblk2<16,5,0,1><<<1, NT, 0, stream>>>(nullptr, nullptr, nullptr, h32, c32,
                                           pE, bias, nullptr, nullptr, out);

  (void)in_sizes; (void)n_in; (void)out_size; (void)ws_size;
}

// Round 16
// 95.920 us; speedup vs baseline: 1.2946x; 1.2946x over previous
//
#include <hip/hip_runtime.h>

#define HH 128
#define NT 512
#define PT 256

typedef float  f32x4  __attribute__((ext_vector_type(4)));
typedef _Float16 f16x8 __attribute__((ext_vector_type(8)));

// pack two f32 -> u32 of 2 fp16, RNE (v_cvt_f16_f32 x2 + pack)
static __device__ __forceinline__ unsigned int pk16(float a, float b){
  unsigned short ha = __builtin_bit_cast(unsigned short, (_Float16)a);
  unsigned short hb = __builtin_bit_cast(unsigned short, (_Float16)b);
  return (unsigned int)ha | ((unsigned int)hb << 16);
}
static __device__ __forceinline__ float f16_to_f(unsigned short s){
  return (float)__builtin_bit_cast(_Float16, s);
}

__device__ __forceinline__ float sigf(float x){
  float t = __builtin_amdgcn_exp2f(-1.44269504089f * x);
  return __builtin_amdgcn_rcpf(1.f + t);
}
__device__ __forceinline__ float tanhf_(float x){
  float t = __builtin_amdgcn_exp2f(2.88539008178f * x);
  return 1.f - 2.f*__builtin_amdgcn_rcpf(t + 1.f);
}

// Pack W into MFMA-B-fragment order, single fp16 RNE plane each.
//  eff (internal): we = W[g][k] + 0.5*W[g][128+k];  leaf: wl = W[g][128+k]
// Pack index: (((wp*8 + q*2 + ft)*4 + kc)*64 + lane)*8 + j
__global__ __launch_bounds__(PT) void prep_pack(
    const float* __restrict__ W,
    unsigned short* __restrict__ pE, unsigned short* __restrict__ pL)
{
  int idx = blockIdx.x*PT + threadIdx.x;     // 0..8191
  int l  = idx & 63;
  int kc = (idx >> 6) & 3;
  int gl = (idx >> 8) & 7;
  int wp = (idx >> 11);                      // 0..3
  int q  = gl >> 1, ft = gl & 1;
  int g  = q*128 + wp*32 + ft*16 + (l & 15);
  int kbase = kc*32 + (l >> 4)*8;

  unsigned short ev[8], lv[8];
#pragma unroll
  for (int j = 0; j < 8; ++j){
    int k = kbase + j;
    float w0 = W[g*256 + k];
    float w1 = W[g*256 + 128 + k];
    float we = w0 + 0.5f*w1;
    ev[j] = __builtin_bit_cast(unsigned short, (_Float16)we);
    lv[j] = __builtin_bit_cast(unsigned short, (_Float16)w1);
  }
  long base = (long)idx*8;
  *(f16x8*)&pE[base] = *(f16x8*)ev;
  *(f16x8*)&pL[base] = *(f16x8*)lv;
}

// ---------------- leaf kernel: L0 only, single-plane fp16 A ------------------
__global__ __launch_bounds__(NT, 2) void leafK(
    const float* __restrict__ x_leaf,
    const unsigned short* __restrict__ pL,
    const float* __restrict__ bias,
    unsigned short* __restrict__ HpO,
    float* __restrict__ csO, int ntiles)
{
  __shared__ unsigned short AsH[2][32*HH];

  const int t = threadIdx.x, w = t>>6, l = t&63;
  const int a = l>>4, fcol = l&15, feat = w*16 + fcol;

  // resident leaf-B (gates i,g,o): 12 frags = 48 VGPRs
  f16x8 rb[3][4];
#pragma unroll
  for (int qq = 0; qq < 3; ++qq)
#pragma unroll
    for (int kc = 0; kc < 4; ++kc){
      long off = ((long)((((w>>1)*8) + (qq+1)*2 + (w&1))*4 + kc)*64 + l)*8;
      rb[qq][kc] = *(const f16x8*)&pL[off];
    }
  const float Bi = bias[HH + feat], Bg = bias[2*HH + feat], Bo = bias[3*HH + feat];

  const int srow = t>>4, sci = t&15;
  float sv[8];
  auto sload = [&](int tile){
    long base = ((long)tile*32 + srow)*HH + sci*8;
    *(float4*)&sv[0] = *(const float4*)&x_leaf[base];
    *(float4*)&sv[4] = *(const float4*)&x_leaf[base+4];
  };
  auto swrite = [&](int buf){
    unsigned int hp[4];
#pragma unroll
    for (int p = 0; p < 4; ++p) hp[p] = pk16(sv[2*p], sv[2*p+1]);
    uint4 hq = {hp[0],hp[1],hp[2],hp[3]};
    int off = srow*256 + ((sci*16) ^ ((srow&7)<<4));
    *(uint4*)((char*)&AsH[buf][0] + off) = hq;
  };

  int tile = blockIdx.x;
  if (tile < ntiles){ sload(tile); swrite(0); }
  __syncthreads();
  int buf = 0;

  for (; tile < ntiles; tile += gridDim.x){
    // keep B loop-carried
#pragma unroll
    for (int qq = 0; qq < 3; ++qq)
#pragma unroll
      for (int kc = 0; kc < 4; ++kc)
        asm volatile("" : "+v"(rb[qq][kc]));

    int nxt = tile + gridDim.x;
    bool have = nxt < ntiles;
    if (have) sload(nxt);

    f32x4 acc[2][3];
#pragma unroll
    for (int mt = 0; mt < 2; ++mt)
#pragma unroll
      for (int qq = 0; qq < 3; ++qq) acc[mt][qq] = (f32x4)(0.f);

#pragma unroll
    for (int kc = 0; kc < 4; ++kc){
      f16x8 aH[2];
#pragma unroll
      for (int mt = 0; mt < 2; ++mt){
        int row = mt*16 + fcol;
        int off = row*256 + ((kc*64 + a*16) ^ ((row&7)<<4));
        aH[mt] = *(const f16x8*)((const char*)&AsH[buf][0] + off);
      }
#pragma unroll
      for (int qq = 0; qq < 3; ++qq)
#pragma unroll
        for (int mt = 0; mt < 2; ++mt)
          acc[mt][qq] = __builtin_amdgcn_mfma_f32_16x16x32_f16(aH[mt], rb[qq][kc], acc[mt][qq], 0, 0, 0);
    }

    // epilogue (cc = 0): pair-sum fp16 h plane + f32 cs plane
#pragma unroll
    for (int mt = 0; mt < 2; ++mt){
      float hv[4], cv[4];
#pragma unroll
      for (int rr = 0; rr < 4; ++rr){
        float iv = acc[mt][0][rr] + Bi;
        float gv = acc[mt][1][rr] + Bg;
        float ov = acc[mt][2][rr] + Bo;
        float c = sigf(iv)*tanhf_(gv);
        float h = sigf(ov)*tanhf_(c);
        hv[rr] = h; cv[rr] = c;
      }
#pragma unroll
      for (int p = 0; p < 2; ++p){
        long prow = (long)tile*16 + mt*8 + a*2 + p;
        float hs = hv[2*p] + hv[2*p+1];
        HpO[prow*HH + feat] = __builtin_bit_cast(unsigned short, (_Float16)hs);
        csO[prow*HH + feat] = cv[2*p] + cv[2*p+1];
      }
    }

    if (have) swrite(buf^1);
    __syncthreads();
    buf ^= 1;
  }
}

// ---------------- fused 2-level internal kernel, single-plane fp16 A --------
__global__ __launch_bounds__(NT, 2) void fuse2(
    const unsigned short* __restrict__ hPH,
    const float* __restrict__ cP,
    const unsigned short* __restrict__ pE,
    const float* __restrict__ bias,
    unsigned short* __restrict__ HpO,
    float* __restrict__ csO, int ntiles)
{
  __shared__ unsigned short AsH[2][32*HH];
  __shared__ float HsF[16*HH];
  __shared__ float CsF[16*HH];

  const int t = threadIdx.x, w = t>>6, l = t&63;
  const int a = l>>4, fcol = l&15, feat = w*16 + fcol;

  f16x8 rb[4][4];   // 16 frags = 64 VGPR
#pragma unroll
  for (int q = 0; q < 4; ++q)
#pragma unroll
    for (int kc = 0; kc < 4; ++kc){
      long off = ((long)((((w>>1)*8) + q*2 + (w&1))*4 + kc)*64 + l)*8;
      rb[q][kc] = *(const f16x8*)&pE[off];
    }
  float B4[4];
#pragma unroll
  for (int q = 0; q < 4; ++q) B4[q] = bias[q*HH + feat];

  const int srow = t>>4, sci = t&15;
  f16x8 svH;
  auto sload = [&](int tile){
    long base = ((long)tile*32 + srow)*HH + sci*8;
    svH = *(const f16x8*)&hPH[base];
  };
  auto swrite = [&](int buf){
    int off = srow*256 + ((sci*16) ^ ((srow&7)<<4));
    *(f16x8*)((char*)&AsH[buf][0] + off) = svH;
  };

  int tile = blockIdx.x;
  if (tile < ntiles){ sload(tile); swrite(0); }
  __syncthreads();
  int buf = 0;

  for (; tile < ntiles; tile += gridDim.x){
#pragma unroll
    for (int q = 0; q < 4; ++q)
#pragma unroll
      for (int kc = 0; kc < 4; ++kc)
        asm volatile("" : "+v"(rb[q][kc]));

    int nxt = tile + gridDim.x;
    bool have = nxt < ntiles;

    float cc0[2][4];
#pragma unroll
    for (int mt = 0; mt < 2; ++mt)
#pragma unroll
      for (int rr = 0; rr < 4; ++rr)
        cc0[mt][rr] = cP[((long)tile*32 + mt*16 + a*4 + rr)*HH + feat];

    if (have) sload(nxt);

    // ---- MFMA-0: level A over 32 rows ----
    f32x4 acc0[2][4];
#pragma unroll
    for (int mt = 0; mt < 2; ++mt)
#pragma unroll
      for (int q = 0; q < 4; ++q) acc0[mt][q] = (f32x4)(0.f);

#pragma unroll
    for (int kc = 0; kc < 4; ++kc){
      f16x8 aH[2];
#pragma unroll
      for (int mt = 0; mt < 2; ++mt){
        int row = mt*16 + fcol;
        int off = row*256 + ((kc*64 + a*16) ^ ((row&7)<<4));
        aH[mt] = *(const f16x8*)((const char*)&AsH[buf][0] + off);
      }
#pragma unroll
      for (int q = 0; q < 4; ++q)
#pragma unroll
        for (int mt = 0; mt < 2; ++mt)
          acc0[mt][q] = __builtin_amdgcn_mfma_f32_16x16x32_f16(aH[mt], rb[q][kc], acc0[mt][q], 0, 0, 0);
    }

    // ---- epilogue-0 -> LDS pair-sums (swizzled fp32) ----
#pragma unroll
    for (int mt = 0; mt < 2; ++mt){
      float hv[4], cv[4];
#pragma unroll
      for (int rr = 0; rr < 4; ++rr){
        float fv = acc0[mt][0][rr] + B4[0];
        float iv = acc0[mt][1][rr] + B4[1];
        float gv = acc0[mt][2][rr] + B4[2];
        float ov = acc0[mt][3][rr] + B4[3];
        float c = sigf(fv)*cc0[mt][rr] + sigf(iv)*tanhf_(gv);
        float h = sigf(ov)*tanhf_(c);
        hv[rr] = h; cv[rr] = c;
      }
#pragma unroll
      for (int p = 0; p < 2; ++p){
        int row1 = mt*8 + a*2 + p;
        int o1 = row1*512 + ((feat*4) ^ ((row1&7)<<4));
        *(float*)((char*)HsF + o1) = hv[2*p] + hv[2*p+1];
        *(float*)((char*)CsF + o1) = cv[2*p] + cv[2*p+1];
      }
    }
    if (have) swrite(buf^1);
    __syncthreads();

    // ---- MFMA-1: level B over 16 rows ----
    f32x4 acc1[4];
#pragma unroll
    for (int q = 0; q < 4; ++q) acc1[q] = (f32x4)(0.f);

#pragma unroll
    for (int kc = 0; kc < 4; ++kc){
      f16x8 a1H;
      {
        int cb = kc*128 + a*32;
        const char* base = (const char*)HsF + fcol*512;
        float av[8];
        *(float4*)&av[0] = *(const float4*)(base + ( cb       ^ ((fcol&7)<<4)));
        *(float4*)&av[4] = *(const float4*)(base + ((cb + 16) ^ ((fcol&7)<<4)));
        unsigned int hp[4];
#pragma unroll
        for (int p = 0; p < 4; ++p) hp[p] = pk16(av[2*p], av[2*p+1]);
        uint4 hq = {hp[0],hp[1],hp[2],hp[3]};
        a1H = *(f16x8*)&hq;
      }
#pragma unroll
      for (int q = 0; q < 4; ++q)
        acc1[q] = __builtin_amdgcn_mfma_f32_16x16x32_f16(a1H, rb[q][kc], acc1[q], 0, 0, 0);
    }

    // ---- epilogue-1 -> global planes ----
    {
      float hv[4], cv[4];
#pragma unroll
      for (int rr = 0; rr < 4; ++rr){
        int n = a*4 + rr;
        float ccv = *(const float*)((const char*)CsF + n*512 + ((feat*4) ^ ((n&7)<<4)));
        float fv = acc1[0][rr] + B4[0];
        float iv = acc1[1][rr] + B4[1];
        float gv = acc1[2][rr] + B4[2];
        float ov = acc1[3][rr] + B4[3];
        float c = sigf(fv)*ccv + sigf(iv)*tanhf_(gv);
        float h = sigf(ov)*tanhf_(c);
        hv[rr] = h; cv[rr] = c;
      }
#pragma unroll
      for (int p = 0; p < 2; ++p){
        long prow = (long)tile*8 + a*2 + p;
        float hs = hv[2*p] + hv[2*p+1];
        HpO[prow*HH + feat] = __builtin_bit_cast(unsigned short, (_Float16)hs);
        csO[prow*HH + feat] = cv[2*p] + cv[2*p+1];
      }
    }
    __syncthreads();
    buf ^= 1;
  }
}

// ---------------- multi-level tail block (generic, single-plane A) ----------
template<int ROWS0, int NLEV, int INPLANES, int FINAL>
__global__ __launch_bounds__(NT, 2) void treeblk2(
    const unsigned short* __restrict__ Hp,
    const float* __restrict__ cs,
    const float* __restrict__ hraw, const float* __restrict__ craw,
    const unsigned short* __restrict__ pE,
    const float* __restrict__ bias,
    float* __restrict__ h_out, float* __restrict__ c_out,
    float* __restrict__ root_out)
{
  constexpr int MT = (ROWS0 >= 16) ? (ROWS0/16) : 1;
  __shared__ float Asum[ROWS0][132];
  __shared__ float Csum[ROWS0][132];

  const int t = threadIdx.x;
  const long blk = blockIdx.x;
  const int w = t >> 6, l = t & 63;
  const int a = l >> 4, fcol = l & 15, feat = w*16 + fcol;

  {
    constexpr int EPT = ROWS0*HH/NT;
    constexpr int TPR = HH/EPT;
    int row = t/TPR, c0 = (t%TPR)*EPT;
    if (INPLANES){
      long base = (blk*ROWS0 + row)*(long)HH + c0;
#pragma unroll
      for (int j = 0; j < EPT; ++j){
        Asum[row][c0+j] = f16_to_f(Hp[base+j]);
        Csum[row][c0+j] = cs[base+j];
      }
    } else {
      long g = (blk*2*ROWS0 + 2*row)*(long)HH + c0;
#pragma unroll
      for (int j = 0; j < EPT; ++j){
        Asum[row][c0+j] = hraw[g+j] + hraw[g+HH+j];
        Csum[row][c0+j] = craw[g+j] + craw[g+HH+j];
      }
    }
  }

  f16x8 rb[4][4];
#pragma unroll
  for (int q = 0; q < 4; ++q)
#pragma unroll
    for (int kc = 0; kc < 4; ++kc){
      long off = ((long)((((w>>1)*8) + q*2 + (w&1))*4 + kc)*64 + l)*8;
      rb[q][kc] = *(const f16x8*)&pE[off];
    }
  float B4[4];
#pragma unroll
  for (int q = 0; q < 4; ++q) B4[q] = bias[q*HH + feat];

  __syncthreads();

#pragma unroll
  for (int lv = 0; lv < NLEV; ++lv){
    const int rows  = ROWS0 >> lv;
    const int tiles = (rows >= 16) ? (rows/16) : 1;
    float hv[MT][4], cv[MT][4];

#pragma unroll
    for (int mt = 0; mt < MT; ++mt){
      if (mt >= tiles) continue;
      f16x8 aH[4];
#pragma unroll
      for (int kc = 0; kc < 4; ++kc){
        const float* ap = &Asum[mt*16 + fcol][kc*32 + a*8];
        float av[8];
        *(float4*)&av[0] = *(const float4*)&ap[0];
        *(float4*)&av[4] = *(const float4*)&ap[4];
        unsigned int hp[4];
#pragma unroll
        for (int p = 0; p < 4; ++p) hp[p] = pk16(av[2*p], av[2*p+1]);
        uint4 hq = {hp[0],hp[1],hp[2],hp[3]};
        aH[kc] = *(f16x8*)&hq;
      }
      f32x4 acc[4];
#pragma unroll
      for (int q = 0; q < 4; ++q) acc[q] = (f32x4)(0.f);
#pragma unroll
      for (int kc = 0; kc < 4; ++kc){
#pragma unroll
        for (int q = 0; q < 4; ++q)
          acc[q] = __builtin_amdgcn_mfma_f32_16x16x32_f16(aH[kc], rb[q][kc], acc[q], 0, 0, 0);
      }
#pragma unroll
      for (int rr = 0; rr < 4; ++rr){
        int n = mt*16 + a*4 + rr;
        float ccv = Csum[n][feat];
        float fv = acc[0][rr] + B4[0];
        float iv = acc[1][rr] + B4[1];
        float gv = acc[2][rr] + B4[2];
        float ov = acc[3][rr] + B4[3];
        float c = sigf(fv)*ccv + sigf(iv)*tanhf_(gv);
        float h = sigf(ov)*tanhf_(c);
        hv[mt][rr] = h; cv[mt][rr] = c;
      }
    }
    __syncthreads();

    if (lv < NLEV-1){
#pragma unroll
      for (int mt = 0; mt < MT; ++mt){
        if (mt >= tiles) continue;
#pragma unroll
        for (int p = 0; p < 2; ++p){
          int n0 = mt*16 + a*4 + 2*p;
          if (n0 < rows){
            int prow = n0 >> 1;
            Asum[prow][feat] = hv[mt][2*p] + hv[mt][2*p+1];
            Csum[prow][feat] = cv[mt][2*p] + cv[mt][2*p+1];
          }
        }
      }
      __syncthreads();
    } else if (FINAL){
      if (a == 0) root_out[feat] = hv[0][0];
    } else {
      if (a == 0){
        h_out[blk*HH + feat] = hv[0][0];
        c_out[blk*HH + feat] = cv[0][0];
      }
    }
  }
}

extern "C" void kernel_launch(void* const* d_in, const int* in_sizes, int n_in,
                              void* d_out, int out_size, void* d_ws, size_t ws_size,
                              hipStream_t stream){
  const float* leaf = (const float*)d_in[0];   // 131072 x 128 f32
  const float* W    = (const float*)d_in[1];   // 512 x 256 f32
  const float* bias = (const float*)d_in[2];   // 512 f32
  float* out = (float*)d_out;                  // 128 f32

  unsigned short* pE  = (unsigned short*)d_ws;      // 65536 u16 each
  unsigned short* pL  = pE + 65536;
  unsigned short* HpA = pL + 65536;                 // 2^16 x 128 u16
  unsigned short* HpB = HpA + (1l<<16)*HH;          // 2^14 x 128 u16
  float* csA = (float*)(HpB + (1l<<14)*HH);         // 2^16 x 128 f32
  float* csB = csA + (1l<<16)*HH;                   // 2^14 x 128 f32
  float* h32 = csB + (1l<<14)*HH;                   // 32 x 128 f32
  float* c32 = h32 + 32*HH;

  prep_pack<<<32, PT, 0, stream>>>(W, pE, pL);

  // L0: 2^17 leaves -> 2^16 pair-rows
  leafK<<<512, NT, 0, stream>>>(leaf, pL, bias, HpA, csA, 4096);
  // L1+L2: 2^16 rows -> 2^14
  fuse2<<<512, NT, 0, stream>>>(HpA, csA, pE, bias, HpB, csB, 2048);
  // L3+L4: 2^14 -> 2^12
  fuse2<<<256, NT, 0, stream>>>(HpB, csB, pE, bias, HpA, csA, 512);
  // L5+L6: 2^12 -> 2^10
  fuse2<<<128, NT, 0, stream>>>(HpA, csA, pE, bias, HpB, csB, 128);
  // L7..L12: 2^10 pair-rows -> 32 raw nodes
  treeblk2<32,6,1,0><<<32, NT, 0, stream>>>(HpB, csB, nullptr, nullptr,
                                            pE, bias, h32, c32, nullptr);
  // L13..L17: 32 raw children -> root
  treeblk2<16,5,0,1><<<1, NT, 0, stream>>>(nullptr, nullptr, h32, c32,
                                           pE, bias, nullptr, nullptr, out);

  (void)in_sizes; (void)n_in; (void)out_size; (void)ws_size;
}